// Round 16
// baseline (381.499 us; speedup 1.0000x reference)
//
#include <hip/hip_runtime.h>
#include <hip/hip_bf16.h>
#include <cstdint>

// ---------------------------------------------------------------------------
// GraphRLAgent: 2-layer GAT (heads=2 then 1) + global mean pool + 2 heads.
// Round 16: two-pass aggregation returns — R15's single-pass gat_agg_x is
// VALU-bound (68% VALUBusy): 32 lanes/half redundantly compute the SAME
// per-edge exp. Pass 1 computes each edge weight once (strided lanes) into
// wbuf + z shfl-reduce; pass 2 is a pure-fma gather with coalesced broadcast
// w reads. Keeps R15's aggregate-first layer-1 (x-space, half the bytes).
// ---------------------------------------------------------------------------

typedef __attribute__((ext_vector_type(8))) short bf16x8;
typedef __attribute__((ext_vector_type(4))) float f32x4;

#define RANGES 8

__device__ __forceinline__ float wave_sum(float v) {
#pragma unroll
    for (int off = 32; off >= 1; off >>= 1) v += __shfl_xor(v, off, 64);
    return v;
}

__device__ __forceinline__ unsigned short f2bf(float f) {
    union { float f; uint32_t u; } c; c.f = f;
    uint32_t u = c.u;
    return (unsigned short)((u + 0x7fffu + ((u >> 16) & 1u)) >> 16);
}

__device__ __forceinline__ float bf2f(unsigned short u) {
    union { uint32_t u; float f; } c; c.u = ((uint32_t)u) << 16;
    return c.f;
}

// ------------------------- B swizzle body (ldW/colOff aware) --------------

template <int K, int FOUT>
__device__ __forceinline__ void swizzle_body(const float* __restrict__ W, int ldW, int colOff,
                                             unsigned short* __restrict__ Bsw, int tid) {
    constexpr int CPW = FOUT / 4, NCT = CPW / 16, KST = K / 32;
    if (tid >= K * FOUT / 8) return;
    int lane = tid & 63;
    int rest = tid >> 6;
    int t = rest % KST; rest /= KST;
    int c = rest % NCT; rest /= NCT;
    int cg_ = rest;
    int quad = lane >> 4, lo = lane & 15;
    int col = colOff + cg_ * CPW + c * 16 + lo;
    unsigned short v[8];
#pragma unroll
    for (int j = 0; j < 8; ++j)
        v[j] = f2bf(W[(t * 32 + quad * 8 + j) * ldW + col]);
    ushort4* dst = (ushort4*)(Bsw + (size_t)tid * 8);
    ushort4 o0, o1;
    o0.x = v[0]; o0.y = v[1]; o0.z = v[2]; o0.w = v[3];
    o1.x = v[4]; o1.y = v[5]; o1.z = v[6]; o1.w = v[7];
    dst[0] = o0; dst[1] = o1;
}

// ------------------------- init: zero + swizzles + v1 = W1^T a ------------

__global__ void init_kernel(const float* __restrict__ W1, const float* __restrict__ W2,
                            const float* __restrict__ a_src1, const float* __restrict__ a_dst1,
                            unsigned short* __restrict__ B1h0, unsigned short* __restrict__ B1h1,
                            unsigned short* __restrict__ B2,
                            float* __restrict__ v1s, float* __restrict__ v1d,
                            int* __restrict__ zbase, int zn4) {
    int b = blockIdx.x;
    if (b < 8)        swizzle_body<128, 128>(W1, 256, 0,   B1h0, b * 256 + threadIdx.x);
    else if (b < 16)  swizzle_body<128, 128>(W1, 256, 128, B1h1, (b - 8) * 256 + threadIdx.x);
    else if (b < 32)  swizzle_body<256, 128>(W2, 128, 0,   B2, (b - 16) * 256 + threadIdx.x);
    else if (b == 32) {
        int t = threadIdx.x, h = t >> 7, k = t & 127;
        float vs = 0.f, vd = 0.f;
        for (int c = 0; c < 128; ++c) {
            float w = W1[k * 256 + h * 128 + c];
            vs += w * a_src1[h * 128 + c];
            vd += w * a_dst1[h * 128 + c];
        }
        v1s[h * 128 + k] = vs;
        v1d[h * 128 + k] = vd;
    } else {
        int i = (b - 33) * 256 + threadIdx.x;
        if (i < zn4) ((int4*)zbase)[i] = make_int4(0, 0, 0, 0);
    }
}

// ------------------------- CSR construction -------------------------------

__global__ void degree_kernel(const int* __restrict__ ei, int* __restrict__ deg,
                              int E, int N) {
    int i = blockIdx.x * blockDim.x + threadIdx.x;
    if (i >= E + N) return;
    int dst = (i < E) ? ei[E + i] : (i - E);
    atomicAdd(&deg[dst], 1);
}

__global__ __launch_bounds__(256) void scan_tiles(int* __restrict__ deg,
                                                  int* __restrict__ tsum, int N) {
    __shared__ int buf[256];
    const int t = threadIdx.x;
    const int base = blockIdx.x * 1024 + t * 4;
    int v[4]; int s = 0;
#pragma unroll
    for (int k = 0; k < 4; ++k) { v[k] = (base + k < N) ? deg[base + k] : 0; s += v[k]; }
    buf[t] = s;
    __syncthreads();
#pragma unroll
    for (int off = 1; off < 256; off <<= 1) {
        int x = (t >= off) ? buf[t - off] : 0;
        __syncthreads();
        buf[t] += x;
        __syncthreads();
    }
    int run = buf[t] - s;
#pragma unroll
    for (int k = 0; k < 4; ++k) {
        if (base + k < N) deg[base + k] = run;
        run += v[k];
    }
    if (t == 255) tsum[blockIdx.x] = buf[255];
}

__global__ __launch_bounds__(256) void scan_add(const int* __restrict__ partial,
                                                const int* __restrict__ tsum,
                                                int* __restrict__ rowptr,
                                                int* __restrict__ cursor, int N, int T) {
    __shared__ int s_toff;
    const int tile = blockIdx.x;
    if (threadIdx.x < 64) {
        int t = threadIdx.x;
        int v = (t < T) ? tsum[t] : 0;
#pragma unroll
        for (int off = 1; off < 64; off <<= 1) {
            int x = __shfl_up(v, off, 64);
            if (t >= off) v += x;
        }
        int toff = (tile == 0) ? 0 : __shfl(v, tile - 1, 64);
        if (t == 0) s_toff = toff;
        if (tile == 0 && t == 63) rowptr[N] = v;
    }
    __syncthreads();
    const int toff = s_toff;
    int i = tile * 1024 + threadIdx.x * 4;
#pragma unroll
    for (int k = 0; k < 4; ++k) {
        if (i + k < N) {
            int r = partial[i + k] + toff;
            rowptr[i + k] = r;
            cursor[i + k] = r;
        }
    }
}

// dst-range-partitioned scatter; dst read first so non-matching lanes skip src.
__global__ void scatter_kernel(const int* __restrict__ ei, int* __restrict__ cursor,
                               int* __restrict__ csr_src, int E, int N,
                               int SBLK, int RSIZE) {
    int r = blockIdx.x / SBLK;
    int i = (blockIdx.x % SBLK) * 256 + threadIdx.x;
    if (i >= E + N) return;
    int dst = (i < E) ? ei[E + i] : (i - E);
    int lo = r * RSIZE;
    if (dst < lo || dst >= lo + RSIZE) return;
    int src = (i < E) ? ei[i] : dst;
    int pos = atomicAdd(&cursor[dst], 1);
    csr_src[pos] = src;
}

// ------------------------- layer-1 attn coefs + x cast --------------------

__global__ void attn1_cast(const float* __restrict__ x, const float* __restrict__ v1s,
                           const float* __restrict__ v1d, float* __restrict__ es1,
                           float* __restrict__ ed1, unsigned short* __restrict__ xbf, int N) {
    int wid = (blockIdx.x * blockDim.x + threadIdx.x) >> 6;
    int lane = threadIdx.x & 63;
    if (wid >= N) return;
    float2 xv = *(const float2*)(x + (size_t)wid * 128 + lane * 2);
    float p0s = xv.x * v1s[lane * 2] + xv.y * v1s[lane * 2 + 1];
    float p1s = xv.x * v1s[128 + lane * 2] + xv.y * v1s[128 + lane * 2 + 1];
    float p0d = xv.x * v1d[lane * 2] + xv.y * v1d[lane * 2 + 1];
    float p1d = xv.x * v1d[128 + lane * 2] + xv.y * v1d[128 + lane * 2 + 1];
    p0s = wave_sum(p0s); p1s = wave_sum(p1s);
    p0d = wave_sum(p0d); p1d = wave_sum(p1d);
    if (lane == 0) {
        es1[wid * 2] = p0s; es1[wid * 2 + 1] = p1s;
        ed1[wid * 2] = p0d; ed1[wid * 2 + 1] = p1d;
    }
    ushort2 o; o.x = f2bf(xv.x); o.y = f2bf(xv.y);
    *(ushort2*)(xbf + (size_t)wid * 128 + lane * 2) = o;
}

// ------------------------- layer-1 aggregation in x-space (two-pass) ------
// Pass 1: lane (lane&31) strides the row, head = lane>>5; each edge's exp
// computed ONCE per head, written to wbuf, z half-wave-reduced. Pass 2:
// pure-fma gather with broadcast w reads. Output aggx[h][n][:] bf16 (/z).

__global__ void gat_agg_x(const unsigned short* __restrict__ xbf,
                          const float* __restrict__ es, const float* __restrict__ ed,
                          float* __restrict__ w,
                          const int* __restrict__ rowptr, const int* __restrict__ csr_src,
                          unsigned short* __restrict__ aggx, int N, int NPAD) {
    int wid = (blockIdx.x * blockDim.x + threadIdx.x) >> 6;
    int lane = threadIdx.x & 63;
    if (wid >= N) return;
    const int rs = rowptr[wid], re = rowptr[wid + 1];
    const int half = lane >> 5, c = lane & 31;
    const float edn = ed[wid * 2 + half];

    float z = 0.f;
    for (int i = rs + c; i < re; i += 32) {
        int s = csr_src[i];
        float e = es[s * 2 + half] + edn;
        e = (e > 0.f) ? e : 0.2f * e;
        float ww = __expf(e);
        z += ww;
        w[i * 2 + half] = ww;
    }
#pragma unroll
    for (int off = 16; off >= 1; off >>= 1) z += __shfl_xor(z, off, 64);
    const float rz = 1.f / (z + 1e-16f);
    __threadfence_block();  // drain vmcnt: same-wave RAW on w

    float4 a0 = {0.f, 0.f, 0.f, 0.f}, a1 = {0.f, 0.f, 0.f, 0.f};
    float4 a2 = {0.f, 0.f, 0.f, 0.f}, a3 = {0.f, 0.f, 0.f, 0.f};
    int i = rs;
    for (; i + 4 <= re; i += 4) {
        int s0 = csr_src[i], s1 = csr_src[i + 1], s2 = csr_src[i + 2], s3 = csr_src[i + 3];
        float w0 = w[i * 2 + half],     w1 = w[i * 2 + 2 + half];
        float w2 = w[i * 2 + 4 + half], w3 = w[i * 2 + 6 + half];
        ushort4 u0 = *(const ushort4*)(xbf + (size_t)s0 * 128 + c * 4);
        ushort4 u1 = *(const ushort4*)(xbf + (size_t)s1 * 128 + c * 4);
        ushort4 u2 = *(const ushort4*)(xbf + (size_t)s2 * 128 + c * 4);
        ushort4 u3 = *(const ushort4*)(xbf + (size_t)s3 * 128 + c * 4);
        a0.x += w0 * bf2f(u0.x); a0.y += w0 * bf2f(u0.y);
        a0.z += w0 * bf2f(u0.z); a0.w += w0 * bf2f(u0.w);
        a1.x += w1 * bf2f(u1.x); a1.y += w1 * bf2f(u1.y);
        a1.z += w1 * bf2f(u1.z); a1.w += w1 * bf2f(u1.w);
        a2.x += w2 * bf2f(u2.x); a2.y += w2 * bf2f(u2.y);
        a2.z += w2 * bf2f(u2.z); a2.w += w2 * bf2f(u2.w);
        a3.x += w3 * bf2f(u3.x); a3.y += w3 * bf2f(u3.y);
        a3.z += w3 * bf2f(u3.z); a3.w += w3 * bf2f(u3.w);
    }
    for (; i < re; ++i) {
        int s0 = csr_src[i];
        float w0 = w[i * 2 + half];
        ushort4 u0 = *(const ushort4*)(xbf + (size_t)s0 * 128 + c * 4);
        a0.x += w0 * bf2f(u0.x); a0.y += w0 * bf2f(u0.y);
        a0.z += w0 * bf2f(u0.z); a0.w += w0 * bf2f(u0.w);
    }
    float ox = (a0.x + a1.x + a2.x + a3.x) * rz;
    float oy = (a0.y + a1.y + a2.y + a3.y) * rz;
    float oz = (a0.z + a1.z + a2.z + a3.z) * rz;
    float ow = (a0.w + a1.w + a2.w + a3.w) * rz;
    ushort4 o;
    o.x = f2bf(ox); o.y = f2bf(oy); o.z = f2bf(oz); o.w = f2bf(ow);
    *(ushort4*)(aggx + ((size_t)half * NPAD + wid) * 128 + c * 4) = o;
}

// ------------------------- layer-1 GEMM: h1 = ELU(aggx@W1 + b1) -----------

__global__ __launch_bounds__(256) void gemm_plain(const unsigned short* __restrict__ Abase,
                                                  const unsigned short* __restrict__ B0,
                                                  const unsigned short* __restrict__ B1sw,
                                                  const float* __restrict__ bias,
                                                  unsigned short* __restrict__ C,
                                                  int N, int NPAD) {
    constexpr int K = 128, FOUT = 128;
    constexpr int CPW = FOUT / 4, NCT = CPW / 16, KST = K / 32;
    const int head = blockIdx.y;
    const unsigned short* A = Abase + (size_t)head * NPAD * 128;
    const unsigned short* Bsw = head ? B1sw : B0;
    const int colOff = head * 128;
    const int tid = threadIdx.x;
    const int wave = tid >> 6, lane = tid & 63;
    const int quad = lane >> 4, lo = lane & 15;
    const int n0 = blockIdx.x * 64;
    const int c0 = wave * CPW;

    bf16x8 bf[NCT][KST];
    {
        const bf16x8* Bp = (const bf16x8*)Bsw;
#pragma unroll
        for (int c = 0; c < NCT; ++c)
#pragma unroll
            for (int t = 0; t < KST; ++t)
                bf[c][t] = Bp[((wave * NCT + c) * KST + t) * 64 + lane];
    }

    f32x4 acc[4][NCT];
#pragma unroll
    for (int r = 0; r < 4; ++r)
#pragma unroll
        for (int c = 0; c < NCT; ++c) acc[r][c] = (f32x4){0.f, 0.f, 0.f, 0.f};

#pragma unroll
    for (int r = 0; r < 4; ++r) {
        const unsigned short* Ar = A + (size_t)(n0 + r * 16 + lo) * K + quad * 8;
#pragma unroll
        for (int t = 0; t < KST; ++t) {
            bf16x8 af = *(const bf16x8*)(Ar + t * 32);
#pragma unroll
            for (int c = 0; c < NCT; ++c)
                acc[r][c] = __builtin_amdgcn_mfma_f32_16x16x32_bf16(af, bf[c][t], acc[r][c],
                                                                   0, 0, 0);
        }
    }

#pragma unroll
    for (int r = 0; r < 4; ++r) {
        int row = n0 + r * 16 + quad * 4;
#pragma unroll
        for (int c = 0; c < NCT; ++c) {
            int col = colOff + c0 + c * 16 + lo;
            float bv = bias[col];
#pragma unroll
            for (int j = 0; j < 4; ++j) {
                if (row + j < N) {
                    float v = acc[r][c][j] + bv;
                    v = (v > 0.f) ? v : __expf(v) - 1.f;
                    C[(size_t)(row + j) * 256 + col] = f2bf(v);
                }
            }
        }
    }
}

// ------------------------- layer-2 GEMM + attn-coef epilogue --------------

__global__ __launch_bounds__(256) void gemm2_kernel(const unsigned short* __restrict__ A,
                                                    const unsigned short* __restrict__ Bsw,
                                                    const float* __restrict__ a_src,
                                                    const float* __restrict__ a_dst,
                                                    float* __restrict__ es, float* __restrict__ ed,
                                                    unsigned short* __restrict__ C, int N) {
    constexpr int K = 256, FOUT = 128;
    constexpr int CPW = FOUT / 4, NCT = CPW / 16, KST = K / 32;
    const int tid = threadIdx.x;
    const int wave = tid >> 6, lane = tid & 63;
    const int quad = lane >> 4, lo = lane & 15;
    const int n0 = blockIdx.x * 64;
    const int c0 = wave * CPW;
    __shared__ float lds_ps[4][64];
    __shared__ float lds_pd[4][64];

    bf16x8 bf[NCT][KST];
    {
        const bf16x8* Bp = (const bf16x8*)Bsw;
#pragma unroll
        for (int c = 0; c < NCT; ++c)
#pragma unroll
            for (int t = 0; t < KST; ++t)
                bf[c][t] = Bp[((wave * NCT + c) * KST + t) * 64 + lane];
    }

    f32x4 acc[4][NCT];
#pragma unroll
    for (int r = 0; r < 4; ++r)
#pragma unroll
        for (int c = 0; c < NCT; ++c) acc[r][c] = (f32x4){0.f, 0.f, 0.f, 0.f};

#pragma unroll
    for (int r = 0; r < 4; ++r) {
        const unsigned short* Ar = A + (size_t)(n0 + r * 16 + lo) * K + quad * 8;
#pragma unroll
        for (int t = 0; t < KST; ++t) {
            bf16x8 af = *(const bf16x8*)(Ar + t * 32);
#pragma unroll
            for (int c = 0; c < NCT; ++c)
                acc[r][c] = __builtin_amdgcn_mfma_f32_16x16x32_bf16(af, bf[c][t], acc[r][c],
                                                                   0, 0, 0);
        }
    }

#pragma unroll
    for (int r = 0; r < 4; ++r) {
        int row = n0 + r * 16 + quad * 4;
#pragma unroll
        for (int c = 0; c < NCT; ++c) {
            int col = c0 + c * 16 + lo;
#pragma unroll
            for (int j = 0; j < 4; ++j)
                if (row + j < N) C[(size_t)(row + j) * FOUT + col] = f2bf(acc[r][c][j]);
        }
    }

    float asv[NCT], adv[NCT];
#pragma unroll
    for (int c = 0; c < NCT; ++c) {
        int col = c0 + c * 16 + lo;
        asv[c] = a_src[col];
        adv[c] = a_dst[col];
    }
#pragma unroll
    for (int r = 0; r < 4; ++r) {
#pragma unroll
        for (int j = 0; j < 4; ++j) {
            float ps = 0.f, pd = 0.f;
#pragma unroll
            for (int c = 0; c < NCT; ++c) { ps += acc[r][c][j] * asv[c]; pd += acc[r][c][j] * adv[c]; }
#pragma unroll
            for (int off = 1; off <= 8; off <<= 1) {
                ps += __shfl_xor(ps, off, 64);
                pd += __shfl_xor(pd, off, 64);
            }
            if (lo == 0) {
                int row_l = r * 16 + quad * 4 + j;
                lds_ps[wave][row_l] = ps;
                lds_pd[wave][row_l] = pd;
            }
        }
    }
    __syncthreads();
    if (tid < 64) {
        int row = tid;
        int n = n0 + row;
        if (n < N) {
            es[n] = lds_ps[0][row] + lds_ps[1][row] + lds_ps[2][row] + lds_ps[3][row];
            ed[n] = lds_pd[0][row] + lds_pd[1][row] + lds_pd[2][row] + lds_pd[3][row];
        }
    }
}

// ------------------------- GAT aggregation, H=1 (two-pass) ----------------

__global__ void gat_agg_h1(const unsigned short* __restrict__ Hpre,
                           const float* __restrict__ es, const float* __restrict__ ed,
                           float* __restrict__ w,
                           const int* __restrict__ rowptr, const int* __restrict__ csr_src,
                           const float* __restrict__ bias, unsigned short* __restrict__ out,
                           int N) {
    int wid = (blockIdx.x * blockDim.x + threadIdx.x) >> 6;
    int lane = threadIdx.x & 63;
    if (wid >= N) return;
    const int rs = rowptr[wid], re = rowptr[wid + 1];
    const int half = lane >> 5, c = lane & 31;
    const float edn = ed[wid];

    float z = 0.f;
    for (int i = rs + lane; i < re; i += 64) {
        int s = csr_src[i];
        float e = es[s] + edn;
        e = (e > 0.f) ? e : 0.2f * e;
        float ww = __expf(e);
        z += ww;
        w[i] = ww;
    }
    z = wave_sum(z);
    const float rz = 1.f / (z + 1e-16f);
    __threadfence_block();  // drain vmcnt: same-wave RAW on w

    float4 a0 = {0.f, 0.f, 0.f, 0.f}, a1 = {0.f, 0.f, 0.f, 0.f};
    float4 a2 = {0.f, 0.f, 0.f, 0.f}, a3 = {0.f, 0.f, 0.f, 0.f};
    int i = rs + half;
    for (; i + 6 < re; i += 8) {
        int s0 = csr_src[i], s1 = csr_src[i + 2], s2 = csr_src[i + 4], s3 = csr_src[i + 6];
        float w0 = w[i], w1 = w[i + 2], w2 = w[i + 4], w3 = w[i + 6];
        ushort4 u0 = *(const ushort4*)(Hpre + (size_t)s0 * 128 + c * 4);
        ushort4 u1 = *(const ushort4*)(Hpre + (size_t)s1 * 128 + c * 4);
        ushort4 u2 = *(const ushort4*)(Hpre + (size_t)s2 * 128 + c * 4);
        ushort4 u3 = *(const ushort4*)(Hpre + (size_t)s3 * 128 + c * 4);
        a0.x += w0 * bf2f(u0.x); a0.y += w0 * bf2f(u0.y);
        a0.z += w0 * bf2f(u0.z); a0.w += w0 * bf2f(u0.w);
        a1.x += w1 * bf2f(u1.x); a1.y += w1 * bf2f(u1.y);
        a1.z += w1 * bf2f(u1.z); a1.w += w1 * bf2f(u1.w);
        a2.x += w2 * bf2f(u2.x); a2.y += w2 * bf2f(u2.y);
        a2.z += w2 * bf2f(u2.z); a2.w += w2 * bf2f(u2.w);
        a3.x += w3 * bf2f(u3.x); a3.y += w3 * bf2f(u3.y);
        a3.z += w3 * bf2f(u3.z); a3.w += w3 * bf2f(u3.w);
    }
    for (; i < re; i += 2) {
        int s0 = csr_src[i];
        float w0 = w[i];
        ushort4 u0 = *(const ushort4*)(Hpre + (size_t)s0 * 128 + c * 4);
        a0.x += w0 * bf2f(u0.x); a0.y += w0 * bf2f(u0.y);
        a0.z += w0 * bf2f(u0.z); a0.w += w0 * bf2f(u0.w);
    }
    float ox = a0.x + a1.x + a2.x + a3.x;
    float oy = a0.y + a1.y + a2.y + a3.y;
    float oz = a0.z + a1.z + a2.z + a3.z;
    float ow = a0.w + a1.w + a2.w + a3.w;
    ox += __shfl_xor(ox, 32, 64);
    oy += __shfl_xor(oy, 32, 64);
    oz += __shfl_xor(oz, 32, 64);
    ow += __shfl_xor(ow, 32, 64);
    if (lane < 32) {
        float4 bv = ((const float4*)bias)[c];
        ox = ox * rz + bv.x; oy = oy * rz + bv.y; oz = oz * rz + bv.z; ow = ow * rz + bv.w;
        ox = (ox > 0.f) ? ox : __expf(ox) - 1.f;
        oy = (oy > 0.f) ? oy : __expf(oy) - 1.f;
        oz = (oz > 0.f) ? oz : __expf(oz) - 1.f;
        ow = (ow > 0.f) ? ow : __expf(ow) - 1.f;
        ushort4 o;
        o.x = f2bf(ox); o.y = f2bf(oy); o.z = f2bf(oz); o.w = f2bf(ow);
        *(ushort4*)(out + (size_t)wid * 128 + c * 4) = o;
    }
}

// ------------------------- global mean pool (chunk-parallel) --------------

#define PCHUNK 256

__global__ __launch_bounds__(256) void pool_partial(const unsigned short* __restrict__ h2,
                                                    const int* __restrict__ batch,
                                                    float* __restrict__ xsum,
                                                    int* __restrict__ cnt, int N) {
    const int base = blockIdx.x * PCHUNK;
    const int rg = threadIdx.x >> 6;
    const int c2 = threadIdx.x & 63;
    float ax = 0.f, ay = 0.f;
    int gcur = -1, run = 0;
    for (int r = rg; r < PCHUNK; r += 4) {
        int i = base + r;
        if (i >= N) break;
        int g = batch[i];
        if (g != gcur) {
            if (gcur >= 0) {
                atomicAdd(&xsum[gcur * 128 + c2 * 2 + 0], ax);
                atomicAdd(&xsum[gcur * 128 + c2 * 2 + 1], ay);
                if (c2 == 0) atomicAdd(&cnt[gcur], run);
            }
            gcur = g; ax = 0.f; ay = 0.f; run = 0;
        }
        ushort2 u = *(const ushort2*)(h2 + (size_t)i * 128 + c2 * 2);
        ax += bf2f(u.x); ay += bf2f(u.y);
        run += 1;
    }
    if (gcur >= 0) {
        atomicAdd(&xsum[gcur * 128 + c2 * 2 + 0], ax);
        atomicAdd(&xsum[gcur * 128 + c2 * 2 + 1], ay);
        if (c2 == 0) atomicAdd(&cnt[gcur], run);
    }
}

// ------------------------- policy / value heads ---------------------------

__global__ void head_kernel(const float* __restrict__ xsum, const int* __restrict__ cnt,
                            const float* __restrict__ Wp, const float* __restrict__ bp,
                            const float* __restrict__ Wv, const float* __restrict__ bv,
                            float* __restrict__ out) {
    int g = blockIdx.x, t = threadIdx.x;  // 64 threads
    __shared__ float p[128];
    float inv = 1.f / fmaxf((float)cnt[g], 1.f);
    p[t] = xsum[g * 128 + t] * inv;
    p[t + 64] = xsum[g * 128 + t + 64] * inv;
    __syncthreads();
    if (t < 32) {
        float acc = bp[t];
        for (int k = 0; k < 128; ++k) acc += p[k] * Wp[k * 32 + t];
        out[g * 32 + t] = acc;
    } else if (t == 32) {
        float acc = bv[0];
        for (int k = 0; k < 128; ++k) acc += p[k] * Wv[k];
        out[64 * 32 + g] = acc;
    }
}

// ---------------------------------------------------------------------------

extern "C" void kernel_launch(void* const* d_in, const int* in_sizes, int n_in,
                              void* d_out, int out_size, void* d_ws, size_t ws_size,
                              hipStream_t stream) {
    const float* x      = (const float*)d_in[0];
    const int*   ei     = (const int*)d_in[1];
    const int*   batch  = (const int*)d_in[2];
    const float* W1     = (const float*)d_in[3];
    const float* a_src1 = (const float*)d_in[4];
    const float* a_dst1 = (const float*)d_in[5];
    const float* b1     = (const float*)d_in[6];
    const float* W2     = (const float*)d_in[7];
    const float* a_src2 = (const float*)d_in[8];
    const float* a_dst2 = (const float*)d_in[9];
    const float* b2     = (const float*)d_in[10];
    const float* Wp     = (const float*)d_in[11];
    const float* bp     = (const float*)d_in[12];
    const float* Wv     = (const float*)d_in[13];
    const float* bv     = (const float*)d_in[14];

    const int N  = in_sizes[0] / 128;
    const int E  = in_sizes[1] / 2;
    const int ET = E + N;
    const int TILES = (N + 1023) / 1024;
    const int NPAD = ((N + 63) / 64) * 64;
    const int NBLK = NPAD / 64;
    const int SBLK = (ET + 255) / 256;
    const int RSIZE = (N + RANGES - 1) / RANGES;
    const int PBLK = (N + PCHUNK - 1) / PCHUNK;

    char* ws = (char*)d_ws;
    size_t off = 0;
    auto alloc = [&](size_t bytes) -> void* {
        void* p = ws + off;
        off = (off + bytes + 255) & ~(size_t)255;
        return p;
    };
    unsigned short* xbf   = (unsigned short*)alloc((size_t)NPAD * 128 * 2);
    unsigned short* aggx  = (unsigned short*)alloc((size_t)2 * NPAD * 128 * 2);
    unsigned short* h1bf  = (unsigned short*)alloc((size_t)NPAD * 256 * 2);
    unsigned short* h2pre = (unsigned short*)alloc((size_t)NPAD * 128 * 2);
    unsigned short* h2bf  = (unsigned short*)alloc((size_t)N * 128 * 2);
    unsigned short* w1h0  = (unsigned short*)alloc((size_t)128 * 128 * 2);
    unsigned short* w1h1  = (unsigned short*)alloc((size_t)128 * 128 * 2);
    unsigned short* w2sw  = (unsigned short*)alloc((size_t)256 * 128 * 2);
    float* wbuf = (float*)alloc((size_t)ET * 2 * 4);
    float* v1s = (float*)alloc(256 * 4);
    float* v1d = (float*)alloc(256 * 4);
    float* es1 = (float*)alloc((size_t)N * 2 * 4);
    float* ed1 = (float*)alloc((size_t)N * 2 * 4);
    float* es2 = (float*)alloc((size_t)N * 4);
    float* ed2 = (float*)alloc((size_t)N * 4);
    // contiguous zero region: deg | xsum | cnt
    const int ZINTS = N + 64 * 128 + 64;
    int*   zbase  = (int*)alloc(((size_t)ZINTS + 8) * 4);
    int*   deg    = zbase;
    float* xsum   = (float*)(zbase + N);
    int*   cnt    = (int*)(xsum + 64 * 128);
    int*   rowptr = (int*)alloc((size_t)(N + 1) * 4);
    int*   cursor = (int*)alloc((size_t)N * 4);
    int*   csrsrc = (int*)alloc((size_t)ET * 4);
    int*   tsum   = (int*)alloc(64 * 4);
    const int zn4 = (ZINTS + 3) / 4;

    // --- init: swizzles + v1 + zero, one launch ---
    init_kernel<<<33 + (zn4 + 255) / 256, 256, 0, stream>>>(W1, W2, a_src1, a_dst1,
                                                            w1h0, w1h1, w2sw, v1s, v1d,
                                                            zbase, zn4);

    // --- CSR build ---
    degree_kernel<<<(ET + 255) / 256, 256, 0, stream>>>(ei, deg, E, N);
    scan_tiles<<<TILES, 256, 0, stream>>>(deg, tsum, N);
    scan_add<<<TILES, 256, 0, stream>>>(deg, tsum, rowptr, cursor, N, TILES);
    scatter_kernel<<<RANGES * SBLK, 256, 0, stream>>>(ei, cursor, csrsrc, E, N, SBLK, RSIZE);

    // --- layer 1 (aggregate-first): es1/ed1 + xbf -> agg in x-space -> GEMM ---
    attn1_cast<<<(N + 3) / 4, 256, 0, stream>>>(x, v1s, v1d, es1, ed1, xbf, N);
    gat_agg_x<<<(N + 3) / 4, 256, 0, stream>>>(xbf, es1, ed1, wbuf, rowptr, csrsrc,
                                               aggx, N, NPAD);
    gemm_plain<<<dim3(NBLK, 2), 256, 0, stream>>>(aggx, w1h0, w1h1, b1, h1bf, N, NPAD);

    // --- layer 2 (GEMM-first, already in the smaller space) ---
    gemm2_kernel<<<NBLK, 256, 0, stream>>>(h1bf, w2sw, a_src2, a_dst2, es2, ed2, h2pre, N);
    gat_agg_h1<<<(N + 3) / 4, 256, 0, stream>>>(h2pre, es2, ed2, wbuf, rowptr, csrsrc, b2,
                                                h2bf, N);

    // --- pool + heads ---
    pool_partial<<<PBLK, 256, 0, stream>>>(h2bf, batch, xsum, cnt, N);
    head_kernel<<<64, 64, 0, stream>>>(xsum, cnt, Wp, bp, Wv, bv, (float*)d_out);
}

// Round 17
// 362.865 us; speedup vs baseline: 1.0514x; 1.0514x over previous
//
#include <hip/hip_runtime.h>
#include <hip/hip_bf16.h>
#include <cstdint>

// ---------------------------------------------------------------------------
// GraphRLAgent: 2-layer GAT (heads=2 then 1) + global mean pool + 2 heads.
// Round 17: chunked LDS two-pass aggregation — exp computed ONCE per edge
// (R16's win) with the w staging in per-wave LDS instead of global (kills
// R16's 7MB wbuf write + re-read). Pass 2 reads (s,w) as broadcast ds_read
// (conflict-free) and is a pure-fma gather. Keeps aggregate-first layer 1.
// ---------------------------------------------------------------------------

typedef __attribute__((ext_vector_type(8))) short bf16x8;
typedef __attribute__((ext_vector_type(4))) float f32x4;

#define RANGES 8

__device__ __forceinline__ float wave_sum(float v) {
#pragma unroll
    for (int off = 32; off >= 1; off >>= 1) v += __shfl_xor(v, off, 64);
    return v;
}

__device__ __forceinline__ unsigned short f2bf(float f) {
    union { float f; uint32_t u; } c; c.f = f;
    uint32_t u = c.u;
    return (unsigned short)((u + 0x7fffu + ((u >> 16) & 1u)) >> 16);
}

__device__ __forceinline__ float bf2f(unsigned short u) {
    union { uint32_t u; float f; } c; c.u = ((uint32_t)u) << 16;
    return c.f;
}

// ------------------------- B swizzle body (ldW/colOff aware) --------------

template <int K, int FOUT>
__device__ __forceinline__ void swizzle_body(const float* __restrict__ W, int ldW, int colOff,
                                             unsigned short* __restrict__ Bsw, int tid) {
    constexpr int CPW = FOUT / 4, NCT = CPW / 16, KST = K / 32;
    if (tid >= K * FOUT / 8) return;
    int lane = tid & 63;
    int rest = tid >> 6;
    int t = rest % KST; rest /= KST;
    int c = rest % NCT; rest /= NCT;
    int cg_ = rest;
    int quad = lane >> 4, lo = lane & 15;
    int col = colOff + cg_ * CPW + c * 16 + lo;
    unsigned short v[8];
#pragma unroll
    for (int j = 0; j < 8; ++j)
        v[j] = f2bf(W[(t * 32 + quad * 8 + j) * ldW + col]);
    ushort4* dst = (ushort4*)(Bsw + (size_t)tid * 8);
    ushort4 o0, o1;
    o0.x = v[0]; o0.y = v[1]; o0.z = v[2]; o0.w = v[3];
    o1.x = v[4]; o1.y = v[5]; o1.z = v[6]; o1.w = v[7];
    dst[0] = o0; dst[1] = o1;
}

// ------------------------- init: zero + swizzles + v1 = W1^T a ------------

__global__ void init_kernel(const float* __restrict__ W1, const float* __restrict__ W2,
                            const float* __restrict__ a_src1, const float* __restrict__ a_dst1,
                            unsigned short* __restrict__ B1h0, unsigned short* __restrict__ B1h1,
                            unsigned short* __restrict__ B2,
                            float* __restrict__ v1s, float* __restrict__ v1d,
                            int* __restrict__ zbase, int zn4) {
    int b = blockIdx.x;
    if (b < 8)        swizzle_body<128, 128>(W1, 256, 0,   B1h0, b * 256 + threadIdx.x);
    else if (b < 16)  swizzle_body<128, 128>(W1, 256, 128, B1h1, (b - 8) * 256 + threadIdx.x);
    else if (b < 32)  swizzle_body<256, 128>(W2, 128, 0,   B2, (b - 16) * 256 + threadIdx.x);
    else if (b == 32) {
        int t = threadIdx.x, h = t >> 7, k = t & 127;
        float vs = 0.f, vd = 0.f;
        for (int c = 0; c < 128; ++c) {
            float w = W1[k * 256 + h * 128 + c];
            vs += w * a_src1[h * 128 + c];
            vd += w * a_dst1[h * 128 + c];
        }
        v1s[h * 128 + k] = vs;
        v1d[h * 128 + k] = vd;
    } else {
        int i = (b - 33) * 256 + threadIdx.x;
        if (i < zn4) ((int4*)zbase)[i] = make_int4(0, 0, 0, 0);
    }
}

// ------------------------- CSR construction -------------------------------

__global__ void degree_kernel(const int* __restrict__ ei, int* __restrict__ deg,
                              int E, int N) {
    int i = blockIdx.x * blockDim.x + threadIdx.x;
    if (i >= E + N) return;
    int dst = (i < E) ? ei[E + i] : (i - E);
    atomicAdd(&deg[dst], 1);
}

__global__ __launch_bounds__(256) void scan_tiles(int* __restrict__ deg,
                                                  int* __restrict__ tsum, int N) {
    __shared__ int buf[256];
    const int t = threadIdx.x;
    const int base = blockIdx.x * 1024 + t * 4;
    int v[4]; int s = 0;
#pragma unroll
    for (int k = 0; k < 4; ++k) { v[k] = (base + k < N) ? deg[base + k] : 0; s += v[k]; }
    buf[t] = s;
    __syncthreads();
#pragma unroll
    for (int off = 1; off < 256; off <<= 1) {
        int x = (t >= off) ? buf[t - off] : 0;
        __syncthreads();
        buf[t] += x;
        __syncthreads();
    }
    int run = buf[t] - s;
#pragma unroll
    for (int k = 0; k < 4; ++k) {
        if (base + k < N) deg[base + k] = run;
        run += v[k];
    }
    if (t == 255) tsum[blockIdx.x] = buf[255];
}

__global__ __launch_bounds__(256) void scan_add(const int* __restrict__ partial,
                                                const int* __restrict__ tsum,
                                                int* __restrict__ rowptr,
                                                int* __restrict__ cursor, int N, int T) {
    __shared__ int s_toff;
    const int tile = blockIdx.x;
    if (threadIdx.x < 64) {
        int t = threadIdx.x;
        int v = (t < T) ? tsum[t] : 0;
#pragma unroll
        for (int off = 1; off < 64; off <<= 1) {
            int x = __shfl_up(v, off, 64);
            if (t >= off) v += x;
        }
        int toff = (tile == 0) ? 0 : __shfl(v, tile - 1, 64);
        if (t == 0) s_toff = toff;
        if (tile == 0 && t == 63) rowptr[N] = v;
    }
    __syncthreads();
    const int toff = s_toff;
    int i = tile * 1024 + threadIdx.x * 4;
#pragma unroll
    for (int k = 0; k < 4; ++k) {
        if (i + k < N) {
            int r = partial[i + k] + toff;
            rowptr[i + k] = r;
            cursor[i + k] = r;
        }
    }
}

// dst-range-partitioned scatter; dst read first so non-matching lanes skip src.
__global__ void scatter_kernel(const int* __restrict__ ei, int* __restrict__ cursor,
                               int* __restrict__ csr_src, int E, int N,
                               int SBLK, int RSIZE) {
    int r = blockIdx.x / SBLK;
    int i = (blockIdx.x % SBLK) * 256 + threadIdx.x;
    if (i >= E + N) return;
    int dst = (i < E) ? ei[E + i] : (i - E);
    int lo = r * RSIZE;
    if (dst < lo || dst >= lo + RSIZE) return;
    int src = (i < E) ? ei[i] : dst;
    int pos = atomicAdd(&cursor[dst], 1);
    csr_src[pos] = src;
}

// ------------------------- layer-1 attn coefs + x cast --------------------

__global__ void attn1_cast(const float* __restrict__ x, const float* __restrict__ v1s,
                           const float* __restrict__ v1d, float* __restrict__ es1,
                           float* __restrict__ ed1, unsigned short* __restrict__ xbf, int N) {
    int wid = (blockIdx.x * blockDim.x + threadIdx.x) >> 6;
    int lane = threadIdx.x & 63;
    if (wid >= N) return;
    float2 xv = *(const float2*)(x + (size_t)wid * 128 + lane * 2);
    float p0s = xv.x * v1s[lane * 2] + xv.y * v1s[lane * 2 + 1];
    float p1s = xv.x * v1s[128 + lane * 2] + xv.y * v1s[128 + lane * 2 + 1];
    float p0d = xv.x * v1d[lane * 2] + xv.y * v1d[lane * 2 + 1];
    float p1d = xv.x * v1d[128 + lane * 2] + xv.y * v1d[128 + lane * 2 + 1];
    p0s = wave_sum(p0s); p1s = wave_sum(p1s);
    p0d = wave_sum(p0d); p1d = wave_sum(p1d);
    if (lane == 0) {
        es1[wid * 2] = p0s; es1[wid * 2 + 1] = p1s;
        ed1[wid * 2] = p0d; ed1[wid * 2 + 1] = p1d;
    }
    ushort2 o; o.x = f2bf(xv.x); o.y = f2bf(xv.y);
    *(ushort2*)(xbf + (size_t)wid * 128 + lane * 2) = o;
}

// ------------------------- layer-1 aggregation (LDS two-pass) -------------
// Chunk of 32 edges: lane c computes (s, w=exp(leaky(es+ed))) ONCE for its
// half's head, stages in per-wave LDS; pass 2 reads them back as broadcast
// ds_read and runs the pure-fma gather. Output aggx[h][n][:] bf16 (/z).

__global__ void gat_agg_x(const unsigned short* __restrict__ xbf,
                          const float* __restrict__ es, const float* __restrict__ ed,
                          const int* __restrict__ rowptr, const int* __restrict__ csr_src,
                          unsigned short* __restrict__ aggx, int N, int NPAD) {
    __shared__ float w_lds[4][2][32];
    __shared__ int   s_lds[4][32];
    int wid = (blockIdx.x * blockDim.x + threadIdx.x) >> 6;
    int lane = threadIdx.x & 63;
    if (wid >= N) return;
    const int wave = threadIdx.x >> 6;
    const int rs = rowptr[wid], re = rowptr[wid + 1];
    const int half = lane >> 5, c = lane & 31;
    const float edn = ed[wid * 2 + half];

    float z = 0.f;
    float4 a0 = {0.f, 0.f, 0.f, 0.f}, a1 = {0.f, 0.f, 0.f, 0.f};
    float4 a2 = {0.f, 0.f, 0.f, 0.f}, a3 = {0.f, 0.f, 0.f, 0.f};
    for (int i = rs; i < re; i += 32) {
        const int cnt = min(re - i, 32);
        if (c < cnt) {
            int s = csr_src[i + c];
            float e = es[s * 2 + half] + edn;
            e = (e > 0.f) ? e : 0.2f * e;
            float ww = __expf(e);
            w_lds[wave][half][c] = ww;
            if (half == 0) s_lds[wave][c] = s;
            z += ww;
        }
        // same-wave LDS RAW: compiler inserts lgkmcnt wait
        int k = 0;
        for (; k + 4 <= cnt; k += 4) {
            int s0 = s_lds[wave][k + 0], s1 = s_lds[wave][k + 1];
            int s2 = s_lds[wave][k + 2], s3 = s_lds[wave][k + 3];
            float w0 = w_lds[wave][half][k + 0], w1 = w_lds[wave][half][k + 1];
            float w2 = w_lds[wave][half][k + 2], w3 = w_lds[wave][half][k + 3];
            ushort4 u0 = *(const ushort4*)(xbf + (size_t)s0 * 128 + c * 4);
            ushort4 u1 = *(const ushort4*)(xbf + (size_t)s1 * 128 + c * 4);
            ushort4 u2 = *(const ushort4*)(xbf + (size_t)s2 * 128 + c * 4);
            ushort4 u3 = *(const ushort4*)(xbf + (size_t)s3 * 128 + c * 4);
            a0.x += w0 * bf2f(u0.x); a0.y += w0 * bf2f(u0.y);
            a0.z += w0 * bf2f(u0.z); a0.w += w0 * bf2f(u0.w);
            a1.x += w1 * bf2f(u1.x); a1.y += w1 * bf2f(u1.y);
            a1.z += w1 * bf2f(u1.z); a1.w += w1 * bf2f(u1.w);
            a2.x += w2 * bf2f(u2.x); a2.y += w2 * bf2f(u2.y);
            a2.z += w2 * bf2f(u2.z); a2.w += w2 * bf2f(u2.w);
            a3.x += w3 * bf2f(u3.x); a3.y += w3 * bf2f(u3.y);
            a3.z += w3 * bf2f(u3.z); a3.w += w3 * bf2f(u3.w);
        }
        for (; k < cnt; ++k) {
            int s0 = s_lds[wave][k];
            float w0 = w_lds[wave][half][k];
            ushort4 u0 = *(const ushort4*)(xbf + (size_t)s0 * 128 + c * 4);
            a0.x += w0 * bf2f(u0.x); a0.y += w0 * bf2f(u0.y);
            a0.z += w0 * bf2f(u0.z); a0.w += w0 * bf2f(u0.w);
        }
    }
#pragma unroll
    for (int off = 16; off >= 1; off >>= 1) z += __shfl_xor(z, off, 64);
    const float rz = 1.f / (z + 1e-16f);
    float ox = (a0.x + a1.x + a2.x + a3.x) * rz;
    float oy = (a0.y + a1.y + a2.y + a3.y) * rz;
    float oz = (a0.z + a1.z + a2.z + a3.z) * rz;
    float ow = (a0.w + a1.w + a2.w + a3.w) * rz;
    ushort4 o;
    o.x = f2bf(ox); o.y = f2bf(oy); o.z = f2bf(oz); o.w = f2bf(ow);
    *(ushort4*)(aggx + ((size_t)half * NPAD + wid) * 128 + c * 4) = o;
}

// ------------------------- layer-1 GEMM: h1 = ELU(aggx@W1 + b1) -----------

__global__ __launch_bounds__(256) void gemm_plain(const unsigned short* __restrict__ Abase,
                                                  const unsigned short* __restrict__ B0,
                                                  const unsigned short* __restrict__ B1sw,
                                                  const float* __restrict__ bias,
                                                  unsigned short* __restrict__ C,
                                                  int N, int NPAD) {
    constexpr int K = 128, FOUT = 128;
    constexpr int CPW = FOUT / 4, NCT = CPW / 16, KST = K / 32;
    const int head = blockIdx.y;
    const unsigned short* A = Abase + (size_t)head * NPAD * 128;
    const unsigned short* Bsw = head ? B1sw : B0;
    const int colOff = head * 128;
    const int tid = threadIdx.x;
    const int wave = tid >> 6, lane = tid & 63;
    const int quad = lane >> 4, lo = lane & 15;
    const int n0 = blockIdx.x * 64;
    const int c0 = wave * CPW;

    bf16x8 bf[NCT][KST];
    {
        const bf16x8* Bp = (const bf16x8*)Bsw;
#pragma unroll
        for (int c = 0; c < NCT; ++c)
#pragma unroll
            for (int t = 0; t < KST; ++t)
                bf[c][t] = Bp[((wave * NCT + c) * KST + t) * 64 + lane];
    }

    f32x4 acc[4][NCT];
#pragma unroll
    for (int r = 0; r < 4; ++r)
#pragma unroll
        for (int c = 0; c < NCT; ++c) acc[r][c] = (f32x4){0.f, 0.f, 0.f, 0.f};

#pragma unroll
    for (int r = 0; r < 4; ++r) {
        const unsigned short* Ar = A + (size_t)(n0 + r * 16 + lo) * K + quad * 8;
#pragma unroll
        for (int t = 0; t < KST; ++t) {
            bf16x8 af = *(const bf16x8*)(Ar + t * 32);
#pragma unroll
            for (int c = 0; c < NCT; ++c)
                acc[r][c] = __builtin_amdgcn_mfma_f32_16x16x32_bf16(af, bf[c][t], acc[r][c],
                                                                   0, 0, 0);
        }
    }

#pragma unroll
    for (int r = 0; r < 4; ++r) {
        int row = n0 + r * 16 + quad * 4;
#pragma unroll
        for (int c = 0; c < NCT; ++c) {
            int col = colOff + c0 + c * 16 + lo;
            float bv = bias[col];
#pragma unroll
            for (int j = 0; j < 4; ++j) {
                if (row + j < N) {
                    float v = acc[r][c][j] + bv;
                    v = (v > 0.f) ? v : __expf(v) - 1.f;
                    C[(size_t)(row + j) * 256 + col] = f2bf(v);
                }
            }
        }
    }
}

// ------------------------- layer-2 GEMM + attn-coef epilogue --------------

__global__ __launch_bounds__(256) void gemm2_kernel(const unsigned short* __restrict__ A,
                                                    const unsigned short* __restrict__ Bsw,
                                                    const float* __restrict__ a_src,
                                                    const float* __restrict__ a_dst,
                                                    float* __restrict__ es, float* __restrict__ ed,
                                                    unsigned short* __restrict__ C, int N) {
    constexpr int K = 256, FOUT = 128;
    constexpr int CPW = FOUT / 4, NCT = CPW / 16, KST = K / 32;
    const int tid = threadIdx.x;
    const int wave = tid >> 6, lane = tid & 63;
    const int quad = lane >> 4, lo = lane & 15;
    const int n0 = blockIdx.x * 64;
    const int c0 = wave * CPW;
    __shared__ float lds_ps[4][64];
    __shared__ float lds_pd[4][64];

    bf16x8 bf[NCT][KST];
    {
        const bf16x8* Bp = (const bf16x8*)Bsw;
#pragma unroll
        for (int c = 0; c < NCT; ++c)
#pragma unroll
            for (int t = 0; t < KST; ++t)
                bf[c][t] = Bp[((wave * NCT + c) * KST + t) * 64 + lane];
    }

    f32x4 acc[4][NCT];
#pragma unroll
    for (int r = 0; r < 4; ++r)
#pragma unroll
        for (int c = 0; c < NCT; ++c) acc[r][c] = (f32x4){0.f, 0.f, 0.f, 0.f};

#pragma unroll
    for (int r = 0; r < 4; ++r) {
        const unsigned short* Ar = A + (size_t)(n0 + r * 16 + lo) * K + quad * 8;
#pragma unroll
        for (int t = 0; t < KST; ++t) {
            bf16x8 af = *(const bf16x8*)(Ar + t * 32);
#pragma unroll
            for (int c = 0; c < NCT; ++c)
                acc[r][c] = __builtin_amdgcn_mfma_f32_16x16x32_bf16(af, bf[c][t], acc[r][c],
                                                                   0, 0, 0);
        }
    }

#pragma unroll
    for (int r = 0; r < 4; ++r) {
        int row = n0 + r * 16 + quad * 4;
#pragma unroll
        for (int c = 0; c < NCT; ++c) {
            int col = c0 + c * 16 + lo;
#pragma unroll
            for (int j = 0; j < 4; ++j)
                if (row + j < N) C[(size_t)(row + j) * FOUT + col] = f2bf(acc[r][c][j]);
        }
    }

    float asv[NCT], adv[NCT];
#pragma unroll
    for (int c = 0; c < NCT; ++c) {
        int col = c0 + c * 16 + lo;
        asv[c] = a_src[col];
        adv[c] = a_dst[col];
    }
#pragma unroll
    for (int r = 0; r < 4; ++r) {
#pragma unroll
        for (int j = 0; j < 4; ++j) {
            float ps = 0.f, pd = 0.f;
#pragma unroll
            for (int c = 0; c < NCT; ++c) { ps += acc[r][c][j] * asv[c]; pd += acc[r][c][j] * adv[c]; }
#pragma unroll
            for (int off = 1; off <= 8; off <<= 1) {
                ps += __shfl_xor(ps, off, 64);
                pd += __shfl_xor(pd, off, 64);
            }
            if (lo == 0) {
                int row_l = r * 16 + quad * 4 + j;
                lds_ps[wave][row_l] = ps;
                lds_pd[wave][row_l] = pd;
            }
        }
    }
    __syncthreads();
    if (tid < 64) {
        int row = tid;
        int n = n0 + row;
        if (n < N) {
            es[n] = lds_ps[0][row] + lds_ps[1][row] + lds_ps[2][row] + lds_ps[3][row];
            ed[n] = lds_pd[0][row] + lds_pd[1][row] + lds_pd[2][row] + lds_pd[3][row];
        }
    }
}

// ------------------------- GAT aggregation, H=1 (LDS two-pass) ------------
// Chunk of 64 edges: lane computes its edge's (s,w) once; pass 2 assigns
// half-waves to alternating edges via broadcast ds_reads.

__global__ void gat_agg_h1(const unsigned short* __restrict__ Hpre,
                           const float* __restrict__ es, const float* __restrict__ ed,
                           const int* __restrict__ rowptr, const int* __restrict__ csr_src,
                           const float* __restrict__ bias, unsigned short* __restrict__ out,
                           int N) {
    __shared__ float w_lds[4][64];
    __shared__ int   s_lds[4][64];
    int wid = (blockIdx.x * blockDim.x + threadIdx.x) >> 6;
    int lane = threadIdx.x & 63;
    if (wid >= N) return;
    const int wave = threadIdx.x >> 6;
    const int rs = rowptr[wid], re = rowptr[wid + 1];
    const int half = lane >> 5, c = lane & 31;
    const float edn = ed[wid];

    float z = 0.f;
    float4 a0 = {0.f, 0.f, 0.f, 0.f}, a1 = {0.f, 0.f, 0.f, 0.f};
    float4 a2 = {0.f, 0.f, 0.f, 0.f}, a3 = {0.f, 0.f, 0.f, 0.f};
    for (int i = rs; i < re; i += 64) {
        const int cnt = min(re - i, 64);
        if (lane < cnt) {
            int s = csr_src[i + lane];
            float e = es[s] + edn;
            e = (e > 0.f) ? e : 0.2f * e;
            float ww = __expf(e);
            w_lds[wave][lane] = ww;
            s_lds[wave][lane] = s;
            z += ww;
        }
        // same-wave LDS RAW: compiler inserts lgkmcnt wait
        int k = half;
        for (; k + 6 < cnt; k += 8) {
            int s0 = s_lds[wave][k], s1 = s_lds[wave][k + 2];
            int s2 = s_lds[wave][k + 4], s3 = s_lds[wave][k + 6];
            float w0 = w_lds[wave][k], w1 = w_lds[wave][k + 2];
            float w2 = w_lds[wave][k + 4], w3 = w_lds[wave][k + 6];
            ushort4 u0 = *(const ushort4*)(Hpre + (size_t)s0 * 128 + c * 4);
            ushort4 u1 = *(const ushort4*)(Hpre + (size_t)s1 * 128 + c * 4);
            ushort4 u2 = *(const ushort4*)(Hpre + (size_t)s2 * 128 + c * 4);
            ushort4 u3 = *(const ushort4*)(Hpre + (size_t)s3 * 128 + c * 4);
            a0.x += w0 * bf2f(u0.x); a0.y += w0 * bf2f(u0.y);
            a0.z += w0 * bf2f(u0.z); a0.w += w0 * bf2f(u0.w);
            a1.x += w1 * bf2f(u1.x); a1.y += w1 * bf2f(u1.y);
            a1.z += w1 * bf2f(u1.z); a1.w += w1 * bf2f(u1.w);
            a2.x += w2 * bf2f(u2.x); a2.y += w2 * bf2f(u2.y);
            a2.z += w2 * bf2f(u2.z); a2.w += w2 * bf2f(u2.w);
            a3.x += w3 * bf2f(u3.x); a3.y += w3 * bf2f(u3.y);
            a3.z += w3 * bf2f(u3.z); a3.w += w3 * bf2f(u3.w);
        }
        for (; k < cnt; k += 2) {
            int s0 = s_lds[wave][k];
            float w0 = w_lds[wave][k];
            ushort4 u0 = *(const ushort4*)(Hpre + (size_t)s0 * 128 + c * 4);
            a0.x += w0 * bf2f(u0.x); a0.y += w0 * bf2f(u0.y);
            a0.z += w0 * bf2f(u0.z); a0.w += w0 * bf2f(u0.w);
        }
    }
    z = wave_sum(z);
    const float rz = 1.f / (z + 1e-16f);

    float ox = a0.x + a1.x + a2.x + a3.x;
    float oy = a0.y + a1.y + a2.y + a3.y;
    float oz = a0.z + a1.z + a2.z + a3.z;
    float ow = a0.w + a1.w + a2.w + a3.w;
    ox += __shfl_xor(ox, 32, 64);
    oy += __shfl_xor(oy, 32, 64);
    oz += __shfl_xor(oz, 32, 64);
    ow += __shfl_xor(ow, 32, 64);
    if (lane < 32) {
        float4 bv = ((const float4*)bias)[c];
        ox = ox * rz + bv.x; oy = oy * rz + bv.y; oz = oz * rz + bv.z; ow = ow * rz + bv.w;
        ox = (ox > 0.f) ? ox : __expf(ox) - 1.f;
        oy = (oy > 0.f) ? oy : __expf(oy) - 1.f;
        oz = (oz > 0.f) ? oz : __expf(oz) - 1.f;
        ow = (ow > 0.f) ? ow : __expf(ow) - 1.f;
        ushort4 o;
        o.x = f2bf(ox); o.y = f2bf(oy); o.z = f2bf(oz); o.w = f2bf(ow);
        *(ushort4*)(out + (size_t)wid * 128 + c * 4) = o;
    }
}

// ------------------------- global mean pool (chunk-parallel) --------------

#define PCHUNK 256

__global__ __launch_bounds__(256) void pool_partial(const unsigned short* __restrict__ h2,
                                                    const int* __restrict__ batch,
                                                    float* __restrict__ xsum,
                                                    int* __restrict__ cnt, int N) {
    const int base = blockIdx.x * PCHUNK;
    const int rg = threadIdx.x >> 6;
    const int c2 = threadIdx.x & 63;
    float ax = 0.f, ay = 0.f;
    int gcur = -1, run = 0;
    for (int r = rg; r < PCHUNK; r += 4) {
        int i = base + r;
        if (i >= N) break;
        int g = batch[i];
        if (g != gcur) {
            if (gcur >= 0) {
                atomicAdd(&xsum[gcur * 128 + c2 * 2 + 0], ax);
                atomicAdd(&xsum[gcur * 128 + c2 * 2 + 1], ay);
                if (c2 == 0) atomicAdd(&cnt[gcur], run);
            }
            gcur = g; ax = 0.f; ay = 0.f; run = 0;
        }
        ushort2 u = *(const ushort2*)(h2 + (size_t)i * 128 + c2 * 2);
        ax += bf2f(u.x); ay += bf2f(u.y);
        run += 1;
    }
    if (gcur >= 0) {
        atomicAdd(&xsum[gcur * 128 + c2 * 2 + 0], ax);
        atomicAdd(&xsum[gcur * 128 + c2 * 2 + 1], ay);
        if (c2 == 0) atomicAdd(&cnt[gcur], run);
    }
}

// ------------------------- policy / value heads ---------------------------

__global__ void head_kernel(const float* __restrict__ xsum, const int* __restrict__ cnt,
                            const float* __restrict__ Wp, const float* __restrict__ bp,
                            const float* __restrict__ Wv, const float* __restrict__ bv,
                            float* __restrict__ out) {
    int g = blockIdx.x, t = threadIdx.x;  // 64 threads
    __shared__ float p[128];
    float inv = 1.f / fmaxf((float)cnt[g], 1.f);
    p[t] = xsum[g * 128 + t] * inv;
    p[t + 64] = xsum[g * 128 + t + 64] * inv;
    __syncthreads();
    if (t < 32) {
        float acc = bp[t];
        for (int k = 0; k < 128; ++k) acc += p[k] * Wp[k * 32 + t];
        out[g * 32 + t] = acc;
    } else if (t == 32) {
        float acc = bv[0];
        for (int k = 0; k < 128; ++k) acc += p[k] * Wv[k];
        out[64 * 32 + g] = acc;
    }
}

// ---------------------------------------------------------------------------

extern "C" void kernel_launch(void* const* d_in, const int* in_sizes, int n_in,
                              void* d_out, int out_size, void* d_ws, size_t ws_size,
                              hipStream_t stream) {
    const float* x      = (const float*)d_in[0];
    const int*   ei     = (const int*)d_in[1];
    const int*   batch  = (const int*)d_in[2];
    const float* W1     = (const float*)d_in[3];
    const float* a_src1 = (const float*)d_in[4];
    const float* a_dst1 = (const float*)d_in[5];
    const float* b1     = (const float*)d_in[6];
    const float* W2     = (const float*)d_in[7];
    const float* a_src2 = (const float*)d_in[8];
    const float* a_dst2 = (const float*)d_in[9];
    const float* b2     = (const float*)d_in[10];
    const float* Wp     = (const float*)d_in[11];
    const float* bp     = (const float*)d_in[12];
    const float* Wv     = (const float*)d_in[13];
    const float* bv     = (const float*)d_in[14];

    const int N  = in_sizes[0] / 128;
    const int E  = in_sizes[1] / 2;
    const int ET = E + N;
    const int TILES = (N + 1023) / 1024;
    const int NPAD = ((N + 63) / 64) * 64;
    const int NBLK = NPAD / 64;
    const int SBLK = (ET + 255) / 256;
    const int RSIZE = (N + RANGES - 1) / RANGES;
    const int PBLK = (N + PCHUNK - 1) / PCHUNK;

    char* ws = (char*)d_ws;
    size_t off = 0;
    auto alloc = [&](size_t bytes) -> void* {
        void* p = ws + off;
        off = (off + bytes + 255) & ~(size_t)255;
        return p;
    };
    unsigned short* xbf   = (unsigned short*)alloc((size_t)NPAD * 128 * 2);
    unsigned short* aggx  = (unsigned short*)alloc((size_t)2 * NPAD * 128 * 2);
    unsigned short* h1bf  = (unsigned short*)alloc((size_t)NPAD * 256 * 2);
    unsigned short* h2pre = (unsigned short*)alloc((size_t)NPAD * 128 * 2);
    unsigned short* h2bf  = (unsigned short*)alloc((size_t)N * 128 * 2);
    unsigned short* w1h0  = (unsigned short*)alloc((size_t)128 * 128 * 2);
    unsigned short* w1h1  = (unsigned short*)alloc((size_t)128 * 128 * 2);
    unsigned short* w2sw  = (unsigned short*)alloc((size_t)256 * 128 * 2);
    float* v1s = (float*)alloc(256 * 4);
    float* v1d = (float*)alloc(256 * 4);
    float* es1 = (float*)alloc((size_t)N * 2 * 4);
    float* ed1 = (float*)alloc((size_t)N * 2 * 4);
    float* es2 = (float*)alloc((size_t)N * 4);
    float* ed2 = (float*)alloc((size_t)N * 4);
    // contiguous zero region: deg | xsum | cnt
    const int ZINTS = N + 64 * 128 + 64;
    int*   zbase  = (int*)alloc(((size_t)ZINTS + 8) * 4);
    int*   deg    = zbase;
    float* xsum   = (float*)(zbase + N);
    int*   cnt    = (int*)(xsum + 64 * 128);
    int*   rowptr = (int*)alloc((size_t)(N + 1) * 4);
    int*   cursor = (int*)alloc((size_t)N * 4);
    int*   csrsrc = (int*)alloc((size_t)ET * 4);
    int*   tsum   = (int*)alloc(64 * 4);
    const int zn4 = (ZINTS + 3) / 4;

    // --- init: swizzles + v1 + zero, one launch ---
    init_kernel<<<33 + (zn4 + 255) / 256, 256, 0, stream>>>(W1, W2, a_src1, a_dst1,
                                                            w1h0, w1h1, w2sw, v1s, v1d,
                                                            zbase, zn4);

    // --- CSR build ---
    degree_kernel<<<(ET + 255) / 256, 256, 0, stream>>>(ei, deg, E, N);
    scan_tiles<<<TILES, 256, 0, stream>>>(deg, tsum, N);
    scan_add<<<TILES, 256, 0, stream>>>(deg, tsum, rowptr, cursor, N, TILES);
    scatter_kernel<<<RANGES * SBLK, 256, 0, stream>>>(ei, cursor, csrsrc, E, N, SBLK, RSIZE);

    // --- layer 1 (aggregate-first): es1/ed1 + xbf -> agg in x-space -> GEMM ---
    attn1_cast<<<(N + 3) / 4, 256, 0, stream>>>(x, v1s, v1d, es1, ed1, xbf, N);
    gat_agg_x<<<(N + 3) / 4, 256, 0, stream>>>(xbf, es1, ed1, rowptr, csrsrc, aggx, N, NPAD);
    gemm_plain<<<dim3(NBLK, 2), 256, 0, stream>>>(aggx, w1h0, w1h1, b1, h1bf, N, NPAD);

    // --- layer 2 (GEMM-first, already in the smaller space) ---
    gemm2_kernel<<<NBLK, 256, 0, stream>>>(h1bf, w2sw, a_src2, a_dst2, es2, ed2, h2pre, N);
    gat_agg_h1<<<(N + 3) / 4, 256, 0, stream>>>(h2pre, es2, ed2, rowptr, csrsrc, b2,
                                                h2bf, N);

    // --- pool + heads ---
    pool_partial<<<PBLK, 256, 0, stream>>>(h2bf, batch, xsum, cnt, N);
    head_kernel<<<64, 64, 0, stream>>>(xsum, cnt, Wp, bp, Wv, bv, (float*)d_out);
}

// Round 18
// 341.430 us; speedup vs baseline: 1.1174x; 1.0628x over previous
//
#include <hip/hip_runtime.h>
#include <hip/hip_bf16.h>
#include <cstdint>

// ---------------------------------------------------------------------------
// GraphRLAgent: 2-layer GAT (heads=2 then 1) + global mean pool + 2 heads.
// Round 18: atomic-free scatter. R17's 43us scatter was atomic-bound (850k
// device-scope cursor atomics = 43MB of coherent-point write traffic, NOT the
// range-confined csr stores). degree_kernel already does identical atomics —
// capture their return value as eoff[i] (per-edge within-dst rank), then
// scatter is deterministic: csr[rowptr[dst]+eoff[i]] = src. cursor deleted.
// ---------------------------------------------------------------------------

typedef __attribute__((ext_vector_type(8))) short bf16x8;
typedef __attribute__((ext_vector_type(4))) float f32x4;

#define RANGES 8

__device__ __forceinline__ float wave_sum(float v) {
#pragma unroll
    for (int off = 32; off >= 1; off >>= 1) v += __shfl_xor(v, off, 64);
    return v;
}

__device__ __forceinline__ unsigned short f2bf(float f) {
    union { float f; uint32_t u; } c; c.f = f;
    uint32_t u = c.u;
    return (unsigned short)((u + 0x7fffu + ((u >> 16) & 1u)) >> 16);
}

__device__ __forceinline__ float bf2f(unsigned short u) {
    union { uint32_t u; float f; } c; c.u = ((uint32_t)u) << 16;
    return c.f;
}

// ------------------------- B swizzle body (ldW/colOff aware) --------------

template <int K, int FOUT>
__device__ __forceinline__ void swizzle_body(const float* __restrict__ W, int ldW, int colOff,
                                             unsigned short* __restrict__ Bsw, int tid) {
    constexpr int CPW = FOUT / 4, NCT = CPW / 16, KST = K / 32;
    if (tid >= K * FOUT / 8) return;
    int lane = tid & 63;
    int rest = tid >> 6;
    int t = rest % KST; rest /= KST;
    int c = rest % NCT; rest /= NCT;
    int cg_ = rest;
    int quad = lane >> 4, lo = lane & 15;
    int col = colOff + cg_ * CPW + c * 16 + lo;
    unsigned short v[8];
#pragma unroll
    for (int j = 0; j < 8; ++j)
        v[j] = f2bf(W[(t * 32 + quad * 8 + j) * ldW + col]);
    ushort4* dst = (ushort4*)(Bsw + (size_t)tid * 8);
    ushort4 o0, o1;
    o0.x = v[0]; o0.y = v[1]; o0.z = v[2]; o0.w = v[3];
    o1.x = v[4]; o1.y = v[5]; o1.z = v[6]; o1.w = v[7];
    dst[0] = o0; dst[1] = o1;
}

// ------------------------- init: zero + swizzles + v1 = W1^T a ------------

__global__ void init_kernel(const float* __restrict__ W1, const float* __restrict__ W2,
                            const float* __restrict__ a_src1, const float* __restrict__ a_dst1,
                            unsigned short* __restrict__ B1h0, unsigned short* __restrict__ B1h1,
                            unsigned short* __restrict__ B2,
                            float* __restrict__ v1s, float* __restrict__ v1d,
                            int* __restrict__ zbase, int zn4) {
    int b = blockIdx.x;
    if (b < 8)        swizzle_body<128, 128>(W1, 256, 0,   B1h0, b * 256 + threadIdx.x);
    else if (b < 16)  swizzle_body<128, 128>(W1, 256, 128, B1h1, (b - 8) * 256 + threadIdx.x);
    else if (b < 32)  swizzle_body<256, 128>(W2, 128, 0,   B2, (b - 16) * 256 + threadIdx.x);
    else if (b == 32) {
        int t = threadIdx.x, h = t >> 7, k = t & 127;
        float vs = 0.f, vd = 0.f;
        for (int c = 0; c < 128; ++c) {
            float w = W1[k * 256 + h * 128 + c];
            vs += w * a_src1[h * 128 + c];
            vd += w * a_dst1[h * 128 + c];
        }
        v1s[h * 128 + k] = vs;
        v1d[h * 128 + k] = vd;
    } else {
        int i = (b - 33) * 256 + threadIdx.x;
        if (i < zn4) ((int4*)zbase)[i] = make_int4(0, 0, 0, 0);
    }
}

// ------------------------- CSR construction -------------------------------
// degree + per-edge within-dst rank (the atomic's return value).

__global__ void degree_kernel(const int* __restrict__ ei, int* __restrict__ deg,
                              int* __restrict__ eoff, int E, int N) {
    int i = blockIdx.x * blockDim.x + threadIdx.x;
    if (i >= E + N) return;
    int dst = (i < E) ? ei[E + i] : (i - E);
    eoff[i] = atomicAdd(&deg[dst], 1);
}

__global__ __launch_bounds__(256) void scan_tiles(int* __restrict__ deg,
                                                  int* __restrict__ tsum, int N) {
    __shared__ int buf[256];
    const int t = threadIdx.x;
    const int base = blockIdx.x * 1024 + t * 4;
    int v[4]; int s = 0;
#pragma unroll
    for (int k = 0; k < 4; ++k) { v[k] = (base + k < N) ? deg[base + k] : 0; s += v[k]; }
    buf[t] = s;
    __syncthreads();
#pragma unroll
    for (int off = 1; off < 256; off <<= 1) {
        int x = (t >= off) ? buf[t - off] : 0;
        __syncthreads();
        buf[t] += x;
        __syncthreads();
    }
    int run = buf[t] - s;
#pragma unroll
    for (int k = 0; k < 4; ++k) {
        if (base + k < N) deg[base + k] = run;
        run += v[k];
    }
    if (t == 255) tsum[blockIdx.x] = buf[255];
}

__global__ __launch_bounds__(256) void scan_add(const int* __restrict__ partial,
                                                const int* __restrict__ tsum,
                                                int* __restrict__ rowptr, int N, int T) {
    __shared__ int s_toff;
    const int tile = blockIdx.x;
    if (threadIdx.x < 64) {
        int t = threadIdx.x;
        int v = (t < T) ? tsum[t] : 0;
#pragma unroll
        for (int off = 1; off < 64; off <<= 1) {
            int x = __shfl_up(v, off, 64);
            if (t >= off) v += x;
        }
        int toff = (tile == 0) ? 0 : __shfl(v, tile - 1, 64);
        if (t == 0) s_toff = toff;
        if (tile == 0 && t == 63) rowptr[N] = v;
    }
    __syncthreads();
    const int toff = s_toff;
    int i = tile * 1024 + threadIdx.x * 4;
#pragma unroll
    for (int k = 0; k < 4; ++k) {
        if (i + k < N) rowptr[i + k] = partial[i + k] + toff;
    }
}

// atomic-free, dst-range-partitioned scatter: slot = rowptr[dst] + eoff[i].
__global__ void scatter_kernel(const int* __restrict__ ei, const int* __restrict__ eoff,
                               const int* __restrict__ rowptr, int* __restrict__ csr_src,
                               int E, int N, int SBLK, int RSIZE) {
    int r = blockIdx.x / SBLK;
    int i = (blockIdx.x % SBLK) * 256 + threadIdx.x;
    if (i >= E + N) return;
    int dst = (i < E) ? ei[E + i] : (i - E);
    int lo = r * RSIZE;
    if (dst < lo || dst >= lo + RSIZE) return;
    int src = (i < E) ? ei[i] : dst;
    csr_src[rowptr[dst] + eoff[i]] = src;
}

// ------------------------- layer-1 attn coefs + x cast --------------------

__global__ void attn1_cast(const float* __restrict__ x, const float* __restrict__ v1s,
                           const float* __restrict__ v1d, float* __restrict__ es1,
                           float* __restrict__ ed1, unsigned short* __restrict__ xbf, int N) {
    int wid = (blockIdx.x * blockDim.x + threadIdx.x) >> 6;
    int lane = threadIdx.x & 63;
    if (wid >= N) return;
    float2 xv = *(const float2*)(x + (size_t)wid * 128 + lane * 2);
    float p0s = xv.x * v1s[lane * 2] + xv.y * v1s[lane * 2 + 1];
    float p1s = xv.x * v1s[128 + lane * 2] + xv.y * v1s[128 + lane * 2 + 1];
    float p0d = xv.x * v1d[lane * 2] + xv.y * v1d[lane * 2 + 1];
    float p1d = xv.x * v1d[128 + lane * 2] + xv.y * v1d[128 + lane * 2 + 1];
    p0s = wave_sum(p0s); p1s = wave_sum(p1s);
    p0d = wave_sum(p0d); p1d = wave_sum(p1d);
    if (lane == 0) {
        es1[wid * 2] = p0s; es1[wid * 2 + 1] = p1s;
        ed1[wid * 2] = p0d; ed1[wid * 2 + 1] = p1d;
    }
    ushort2 o; o.x = f2bf(xv.x); o.y = f2bf(xv.y);
    *(ushort2*)(xbf + (size_t)wid * 128 + lane * 2) = o;
}

// ------------------------- layer-1 aggregation (LDS two-pass) -------------

__global__ void gat_agg_x(const unsigned short* __restrict__ xbf,
                          const float* __restrict__ es, const float* __restrict__ ed,
                          const int* __restrict__ rowptr, const int* __restrict__ csr_src,
                          unsigned short* __restrict__ aggx, int N, int NPAD) {
    __shared__ float w_lds[4][2][32];
    __shared__ int   s_lds[4][32];
    int wid = (blockIdx.x * blockDim.x + threadIdx.x) >> 6;
    int lane = threadIdx.x & 63;
    if (wid >= N) return;
    const int wave = threadIdx.x >> 6;
    const int rs = rowptr[wid], re = rowptr[wid + 1];
    const int half = lane >> 5, c = lane & 31;
    const float edn = ed[wid * 2 + half];

    float z = 0.f;
    float4 a0 = {0.f, 0.f, 0.f, 0.f}, a1 = {0.f, 0.f, 0.f, 0.f};
    float4 a2 = {0.f, 0.f, 0.f, 0.f}, a3 = {0.f, 0.f, 0.f, 0.f};
    for (int i = rs; i < re; i += 32) {
        const int cnt = min(re - i, 32);
        if (c < cnt) {
            int s = csr_src[i + c];
            float e = es[s * 2 + half] + edn;
            e = (e > 0.f) ? e : 0.2f * e;
            float ww = __expf(e);
            w_lds[wave][half][c] = ww;
            if (half == 0) s_lds[wave][c] = s;
            z += ww;
        }
        // same-wave LDS RAW: compiler inserts lgkmcnt wait
        int k = 0;
        for (; k + 4 <= cnt; k += 4) {
            int s0 = s_lds[wave][k + 0], s1 = s_lds[wave][k + 1];
            int s2 = s_lds[wave][k + 2], s3 = s_lds[wave][k + 3];
            float w0 = w_lds[wave][half][k + 0], w1 = w_lds[wave][half][k + 1];
            float w2 = w_lds[wave][half][k + 2], w3 = w_lds[wave][half][k + 3];
            ushort4 u0 = *(const ushort4*)(xbf + (size_t)s0 * 128 + c * 4);
            ushort4 u1 = *(const ushort4*)(xbf + (size_t)s1 * 128 + c * 4);
            ushort4 u2 = *(const ushort4*)(xbf + (size_t)s2 * 128 + c * 4);
            ushort4 u3 = *(const ushort4*)(xbf + (size_t)s3 * 128 + c * 4);
            a0.x += w0 * bf2f(u0.x); a0.y += w0 * bf2f(u0.y);
            a0.z += w0 * bf2f(u0.z); a0.w += w0 * bf2f(u0.w);
            a1.x += w1 * bf2f(u1.x); a1.y += w1 * bf2f(u1.y);
            a1.z += w1 * bf2f(u1.z); a1.w += w1 * bf2f(u1.w);
            a2.x += w2 * bf2f(u2.x); a2.y += w2 * bf2f(u2.y);
            a2.z += w2 * bf2f(u2.z); a2.w += w2 * bf2f(u2.w);
            a3.x += w3 * bf2f(u3.x); a3.y += w3 * bf2f(u3.y);
            a3.z += w3 * bf2f(u3.z); a3.w += w3 * bf2f(u3.w);
        }
        for (; k < cnt; ++k) {
            int s0 = s_lds[wave][k];
            float w0 = w_lds[wave][half][k];
            ushort4 u0 = *(const ushort4*)(xbf + (size_t)s0 * 128 + c * 4);
            a0.x += w0 * bf2f(u0.x); a0.y += w0 * bf2f(u0.y);
            a0.z += w0 * bf2f(u0.z); a0.w += w0 * bf2f(u0.w);
        }
    }
#pragma unroll
    for (int off = 16; off >= 1; off >>= 1) z += __shfl_xor(z, off, 64);
    const float rz = 1.f / (z + 1e-16f);
    float ox = (a0.x + a1.x + a2.x + a3.x) * rz;
    float oy = (a0.y + a1.y + a2.y + a3.y) * rz;
    float oz = (a0.z + a1.z + a2.z + a3.z) * rz;
    float ow = (a0.w + a1.w + a2.w + a3.w) * rz;
    ushort4 o;
    o.x = f2bf(ox); o.y = f2bf(oy); o.z = f2bf(oz); o.w = f2bf(ow);
    *(ushort4*)(aggx + ((size_t)half * NPAD + wid) * 128 + c * 4) = o;
}

// ------------------------- layer-1 GEMM: h1 = ELU(aggx@W1 + b1) -----------

__global__ __launch_bounds__(256) void gemm_plain(const unsigned short* __restrict__ Abase,
                                                  const unsigned short* __restrict__ B0,
                                                  const unsigned short* __restrict__ B1sw,
                                                  const float* __restrict__ bias,
                                                  unsigned short* __restrict__ C,
                                                  int N, int NPAD) {
    constexpr int K = 128, FOUT = 128;
    constexpr int CPW = FOUT / 4, NCT = CPW / 16, KST = K / 32;
    const int head = blockIdx.y;
    const unsigned short* A = Abase + (size_t)head * NPAD * 128;
    const unsigned short* Bsw = head ? B1sw : B0;
    const int colOff = head * 128;
    const int tid = threadIdx.x;
    const int wave = tid >> 6, lane = tid & 63;
    const int quad = lane >> 4, lo = lane & 15;
    const int n0 = blockIdx.x * 64;
    const int c0 = wave * CPW;

    bf16x8 bf[NCT][KST];
    {
        const bf16x8* Bp = (const bf16x8*)Bsw;
#pragma unroll
        for (int c = 0; c < NCT; ++c)
#pragma unroll
            for (int t = 0; t < KST; ++t)
                bf[c][t] = Bp[((wave * NCT + c) * KST + t) * 64 + lane];
    }

    f32x4 acc[4][NCT];
#pragma unroll
    for (int r = 0; r < 4; ++r)
#pragma unroll
        for (int c = 0; c < NCT; ++c) acc[r][c] = (f32x4){0.f, 0.f, 0.f, 0.f};

#pragma unroll
    for (int r = 0; r < 4; ++r) {
        const unsigned short* Ar = A + (size_t)(n0 + r * 16 + lo) * K + quad * 8;
#pragma unroll
        for (int t = 0; t < KST; ++t) {
            bf16x8 af = *(const bf16x8*)(Ar + t * 32);
#pragma unroll
            for (int c = 0; c < NCT; ++c)
                acc[r][c] = __builtin_amdgcn_mfma_f32_16x16x32_bf16(af, bf[c][t], acc[r][c],
                                                                   0, 0, 0);
        }
    }

#pragma unroll
    for (int r = 0; r < 4; ++r) {
        int row = n0 + r * 16 + quad * 4;
#pragma unroll
        for (int c = 0; c < NCT; ++c) {
            int col = colOff + c0 + c * 16 + lo;
            float bv = bias[col];
#pragma unroll
            for (int j = 0; j < 4; ++j) {
                if (row + j < N) {
                    float v = acc[r][c][j] + bv;
                    v = (v > 0.f) ? v : __expf(v) - 1.f;
                    C[(size_t)(row + j) * 256 + col] = f2bf(v);
                }
            }
        }
    }
}

// ------------------------- layer-2 GEMM + attn-coef epilogue --------------

__global__ __launch_bounds__(256) void gemm2_kernel(const unsigned short* __restrict__ A,
                                                    const unsigned short* __restrict__ Bsw,
                                                    const float* __restrict__ a_src,
                                                    const float* __restrict__ a_dst,
                                                    float* __restrict__ es, float* __restrict__ ed,
                                                    unsigned short* __restrict__ C, int N) {
    constexpr int K = 256, FOUT = 128;
    constexpr int CPW = FOUT / 4, NCT = CPW / 16, KST = K / 32;
    const int tid = threadIdx.x;
    const int wave = tid >> 6, lane = tid & 63;
    const int quad = lane >> 4, lo = lane & 15;
    const int n0 = blockIdx.x * 64;
    const int c0 = wave * CPW;
    __shared__ float lds_ps[4][64];
    __shared__ float lds_pd[4][64];

    bf16x8 bf[NCT][KST];
    {
        const bf16x8* Bp = (const bf16x8*)Bsw;
#pragma unroll
        for (int c = 0; c < NCT; ++c)
#pragma unroll
            for (int t = 0; t < KST; ++t)
                bf[c][t] = Bp[((wave * NCT + c) * KST + t) * 64 + lane];
    }

    f32x4 acc[4][NCT];
#pragma unroll
    for (int r = 0; r < 4; ++r)
#pragma unroll
        for (int c = 0; c < NCT; ++c) acc[r][c] = (f32x4){0.f, 0.f, 0.f, 0.f};

#pragma unroll
    for (int r = 0; r < 4; ++r) {
        const unsigned short* Ar = A + (size_t)(n0 + r * 16 + lo) * K + quad * 8;
#pragma unroll
        for (int t = 0; t < KST; ++t) {
            bf16x8 af = *(const bf16x8*)(Ar + t * 32);
#pragma unroll
            for (int c = 0; c < NCT; ++c)
                acc[r][c] = __builtin_amdgcn_mfma_f32_16x16x32_bf16(af, bf[c][t], acc[r][c],
                                                                   0, 0, 0);
        }
    }

#pragma unroll
    for (int r = 0; r < 4; ++r) {
        int row = n0 + r * 16 + quad * 4;
#pragma unroll
        for (int c = 0; c < NCT; ++c) {
            int col = c0 + c * 16 + lo;
#pragma unroll
            for (int j = 0; j < 4; ++j)
                if (row + j < N) C[(size_t)(row + j) * FOUT + col] = f2bf(acc[r][c][j]);
        }
    }

    float asv[NCT], adv[NCT];
#pragma unroll
    for (int c = 0; c < NCT; ++c) {
        int col = c0 + c * 16 + lo;
        asv[c] = a_src[col];
        adv[c] = a_dst[col];
    }
#pragma unroll
    for (int r = 0; r < 4; ++r) {
#pragma unroll
        for (int j = 0; j < 4; ++j) {
            float ps = 0.f, pd = 0.f;
#pragma unroll
            for (int c = 0; c < NCT; ++c) { ps += acc[r][c][j] * asv[c]; pd += acc[r][c][j] * adv[c]; }
#pragma unroll
            for (int off = 1; off <= 8; off <<= 1) {
                ps += __shfl_xor(ps, off, 64);
                pd += __shfl_xor(pd, off, 64);
            }
            if (lo == 0) {
                int row_l = r * 16 + quad * 4 + j;
                lds_ps[wave][row_l] = ps;
                lds_pd[wave][row_l] = pd;
            }
        }
    }
    __syncthreads();
    if (tid < 64) {
        int row = tid;
        int n = n0 + row;
        if (n < N) {
            es[n] = lds_ps[0][row] + lds_ps[1][row] + lds_ps[2][row] + lds_ps[3][row];
            ed[n] = lds_pd[0][row] + lds_pd[1][row] + lds_pd[2][row] + lds_pd[3][row];
        }
    }
}

// ------------------------- GAT aggregation, H=1 (LDS two-pass) ------------

__global__ void gat_agg_h1(const unsigned short* __restrict__ Hpre,
                           const float* __restrict__ es, const float* __restrict__ ed,
                           const int* __restrict__ rowptr, const int* __restrict__ csr_src,
                           const float* __restrict__ bias, unsigned short* __restrict__ out,
                           int N) {
    __shared__ float w_lds[4][64];
    __shared__ int   s_lds[4][64];
    int wid = (blockIdx.x * blockDim.x + threadIdx.x) >> 6;
    int lane = threadIdx.x & 63;
    if (wid >= N) return;
    const int wave = threadIdx.x >> 6;
    const int rs = rowptr[wid], re = rowptr[wid + 1];
    const int half = lane >> 5, c = lane & 31;
    const float edn = ed[wid];

    float z = 0.f;
    float4 a0 = {0.f, 0.f, 0.f, 0.f}, a1 = {0.f, 0.f, 0.f, 0.f};
    float4 a2 = {0.f, 0.f, 0.f, 0.f}, a3 = {0.f, 0.f, 0.f, 0.f};
    for (int i = rs; i < re; i += 64) {
        const int cnt = min(re - i, 64);
        if (lane < cnt) {
            int s = csr_src[i + lane];
            float e = es[s] + edn;
            e = (e > 0.f) ? e : 0.2f * e;
            float ww = __expf(e);
            w_lds[wave][lane] = ww;
            s_lds[wave][lane] = s;
            z += ww;
        }
        // same-wave LDS RAW: compiler inserts lgkmcnt wait
        int k = half;
        for (; k + 6 < cnt; k += 8) {
            int s0 = s_lds[wave][k], s1 = s_lds[wave][k + 2];
            int s2 = s_lds[wave][k + 4], s3 = s_lds[wave][k + 6];
            float w0 = w_lds[wave][k], w1 = w_lds[wave][k + 2];
            float w2 = w_lds[wave][k + 4], w3 = w_lds[wave][k + 6];
            ushort4 u0 = *(const ushort4*)(Hpre + (size_t)s0 * 128 + c * 4);
            ushort4 u1 = *(const ushort4*)(Hpre + (size_t)s1 * 128 + c * 4);
            ushort4 u2 = *(const ushort4*)(Hpre + (size_t)s2 * 128 + c * 4);
            ushort4 u3 = *(const ushort4*)(Hpre + (size_t)s3 * 128 + c * 4);
            a0.x += w0 * bf2f(u0.x); a0.y += w0 * bf2f(u0.y);
            a0.z += w0 * bf2f(u0.z); a0.w += w0 * bf2f(u0.w);
            a1.x += w1 * bf2f(u1.x); a1.y += w1 * bf2f(u1.y);
            a1.z += w1 * bf2f(u1.z); a1.w += w1 * bf2f(u1.w);
            a2.x += w2 * bf2f(u2.x); a2.y += w2 * bf2f(u2.y);
            a2.z += w2 * bf2f(u2.z); a2.w += w2 * bf2f(u2.w);
            a3.x += w3 * bf2f(u3.x); a3.y += w3 * bf2f(u3.y);
            a3.z += w3 * bf2f(u3.z); a3.w += w3 * bf2f(u3.w);
        }
        for (; k < cnt; k += 2) {
            int s0 = s_lds[wave][k];
            float w0 = w_lds[wave][k];
            ushort4 u0 = *(const ushort4*)(Hpre + (size_t)s0 * 128 + c * 4);
            a0.x += w0 * bf2f(u0.x); a0.y += w0 * bf2f(u0.y);
            a0.z += w0 * bf2f(u0.z); a0.w += w0 * bf2f(u0.w);
        }
    }
    z = wave_sum(z);
    const float rz = 1.f / (z + 1e-16f);

    float ox = a0.x + a1.x + a2.x + a3.x;
    float oy = a0.y + a1.y + a2.y + a3.y;
    float oz = a0.z + a1.z + a2.z + a3.z;
    float ow = a0.w + a1.w + a2.w + a3.w;
    ox += __shfl_xor(ox, 32, 64);
    oy += __shfl_xor(oy, 32, 64);
    oz += __shfl_xor(oz, 32, 64);
    ow += __shfl_xor(ow, 32, 64);
    if (lane < 32) {
        float4 bv = ((const float4*)bias)[c];
        ox = ox * rz + bv.x; oy = oy * rz + bv.y; oz = oz * rz + bv.z; ow = ow * rz + bv.w;
        ox = (ox > 0.f) ? ox : __expf(ox) - 1.f;
        oy = (oy > 0.f) ? oy : __expf(oy) - 1.f;
        oz = (oz > 0.f) ? oz : __expf(oz) - 1.f;
        ow = (ow > 0.f) ? ow : __expf(ow) - 1.f;
        ushort4 o;
        o.x = f2bf(ox); o.y = f2bf(oy); o.z = f2bf(oz); o.w = f2bf(ow);
        *(ushort4*)(out + (size_t)wid * 128 + c * 4) = o;
    }
}

// ------------------------- global mean pool (chunk-parallel) --------------

#define PCHUNK 256

__global__ __launch_bounds__(256) void pool_partial(const unsigned short* __restrict__ h2,
                                                    const int* __restrict__ batch,
                                                    float* __restrict__ xsum,
                                                    int* __restrict__ cnt, int N) {
    const int base = blockIdx.x * PCHUNK;
    const int rg = threadIdx.x >> 6;
    const int c2 = threadIdx.x & 63;
    float ax = 0.f, ay = 0.f;
    int gcur = -1, run = 0;
    for (int r = rg; r < PCHUNK; r += 4) {
        int i = base + r;
        if (i >= N) break;
        int g = batch[i];
        if (g != gcur) {
            if (gcur >= 0) {
                atomicAdd(&xsum[gcur * 128 + c2 * 2 + 0], ax);
                atomicAdd(&xsum[gcur * 128 + c2 * 2 + 1], ay);
                if (c2 == 0) atomicAdd(&cnt[gcur], run);
            }
            gcur = g; ax = 0.f; ay = 0.f; run = 0;
        }
        ushort2 u = *(const ushort2*)(h2 + (size_t)i * 128 + c2 * 2);
        ax += bf2f(u.x); ay += bf2f(u.y);
        run += 1;
    }
    if (gcur >= 0) {
        atomicAdd(&xsum[gcur * 128 + c2 * 2 + 0], ax);
        atomicAdd(&xsum[gcur * 128 + c2 * 2 + 1], ay);
        if (c2 == 0) atomicAdd(&cnt[gcur], run);
    }
}

// ------------------------- policy / value heads ---------------------------

__global__ void head_kernel(const float* __restrict__ xsum, const int* __restrict__ cnt,
                            const float* __restrict__ Wp, const float* __restrict__ bp,
                            const float* __restrict__ Wv, const float* __restrict__ bv,
                            float* __restrict__ out) {
    int g = blockIdx.x, t = threadIdx.x;  // 64 threads
    __shared__ float p[128];
    float inv = 1.f / fmaxf((float)cnt[g], 1.f);
    p[t] = xsum[g * 128 + t] * inv;
    p[t + 64] = xsum[g * 128 + t + 64] * inv;
    __syncthreads();
    if (t < 32) {
        float acc = bp[t];
        for (int k = 0; k < 128; ++k) acc += p[k] * Wp[k * 32 + t];
        out[g * 32 + t] = acc;
    } else if (t == 32) {
        float acc = bv[0];
        for (int k = 0; k < 128; ++k) acc += p[k] * Wv[k];
        out[64 * 32 + g] = acc;
    }
}

// ---------------------------------------------------------------------------

extern "C" void kernel_launch(void* const* d_in, const int* in_sizes, int n_in,
                              void* d_out, int out_size, void* d_ws, size_t ws_size,
                              hipStream_t stream) {
    const float* x      = (const float*)d_in[0];
    const int*   ei     = (const int*)d_in[1];
    const int*   batch  = (const int*)d_in[2];
    const float* W1     = (const float*)d_in[3];
    const float* a_src1 = (const float*)d_in[4];
    const float* a_dst1 = (const float*)d_in[5];
    const float* b1     = (const float*)d_in[6];
    const float* W2     = (const float*)d_in[7];
    const float* a_src2 = (const float*)d_in[8];
    const float* a_dst2 = (const float*)d_in[9];
    const float* b2     = (const float*)d_in[10];
    const float* Wp     = (const float*)d_in[11];
    const float* bp     = (const float*)d_in[12];
    const float* Wv     = (const float*)d_in[13];
    const float* bv     = (const float*)d_in[14];

    const int N  = in_sizes[0] / 128;
    const int E  = in_sizes[1] / 2;
    const int ET = E + N;
    const int TILES = (N + 1023) / 1024;
    const int NPAD = ((N + 63) / 64) * 64;
    const int NBLK = NPAD / 64;
    const int SBLK = (ET + 255) / 256;
    const int RSIZE = (N + RANGES - 1) / RANGES;
    const int PBLK = (N + PCHUNK - 1) / PCHUNK;

    char* ws = (char*)d_ws;
    size_t off = 0;
    auto alloc = [&](size_t bytes) -> void* {
        void* p = ws + off;
        off = (off + bytes + 255) & ~(size_t)255;
        return p;
    };
    unsigned short* xbf   = (unsigned short*)alloc((size_t)NPAD * 128 * 2);
    unsigned short* aggx  = (unsigned short*)alloc((size_t)2 * NPAD * 128 * 2);
    unsigned short* h1bf  = (unsigned short*)alloc((size_t)NPAD * 256 * 2);
    unsigned short* h2pre = (unsigned short*)alloc((size_t)NPAD * 128 * 2);
    unsigned short* h2bf  = (unsigned short*)alloc((size_t)N * 128 * 2);
    unsigned short* w1h0  = (unsigned short*)alloc((size_t)128 * 128 * 2);
    unsigned short* w1h1  = (unsigned short*)alloc((size_t)128 * 128 * 2);
    unsigned short* w2sw  = (unsigned short*)alloc((size_t)256 * 128 * 2);
    float* v1s = (float*)alloc(256 * 4);
    float* v1d = (float*)alloc(256 * 4);
    float* es1 = (float*)alloc((size_t)N * 2 * 4);
    float* ed1 = (float*)alloc((size_t)N * 2 * 4);
    float* es2 = (float*)alloc((size_t)N * 4);
    float* ed2 = (float*)alloc((size_t)N * 4);
    // contiguous zero region: deg | xsum | cnt
    const int ZINTS = N + 64 * 128 + 64;
    int*   zbase  = (int*)alloc(((size_t)ZINTS + 8) * 4);
    int*   deg    = zbase;
    float* xsum   = (float*)(zbase + N);
    int*   cnt    = (int*)(xsum + 64 * 128);
    int*   rowptr = (int*)alloc((size_t)(N + 1) * 4);
    int*   eoff   = (int*)alloc((size_t)ET * 4);
    int*   csrsrc = (int*)alloc((size_t)ET * 4);
    int*   tsum   = (int*)alloc(64 * 4);
    const int zn4 = (ZINTS + 3) / 4;

    // --- init: swizzles + v1 + zero, one launch ---
    init_kernel<<<33 + (zn4 + 255) / 256, 256, 0, stream>>>(W1, W2, a_src1, a_dst1,
                                                            w1h0, w1h1, w2sw, v1s, v1d,
                                                            zbase, zn4);

    // --- CSR build (atomic-free scatter via eoff = atomic return value) ---
    degree_kernel<<<(ET + 255) / 256, 256, 0, stream>>>(ei, deg, eoff, E, N);
    scan_tiles<<<TILES, 256, 0, stream>>>(deg, tsum, N);
    scan_add<<<TILES, 256, 0, stream>>>(deg, tsum, rowptr, N, TILES);
    scatter_kernel<<<RANGES * SBLK, 256, 0, stream>>>(ei, eoff, rowptr, csrsrc, E, N,
                                                      SBLK, RSIZE);

    // --- layer 1 (aggregate-first): es1/ed1 + xbf -> agg in x-space -> GEMM ---
    attn1_cast<<<(N + 3) / 4, 256, 0, stream>>>(x, v1s, v1d, es1, ed1, xbf, N);
    gat_agg_x<<<(N + 3) / 4, 256, 0, stream>>>(xbf, es1, ed1, rowptr, csrsrc, aggx, N, NPAD);
    gemm_plain<<<dim3(NBLK, 2), 256, 0, stream>>>(aggx, w1h0, w1h1, b1, h1bf, N, NPAD);

    // --- layer 2 (GEMM-first, already in the smaller space) ---
    gemm2_kernel<<<NBLK, 256, 0, stream>>>(h1bf, w2sw, a_src2, a_dst2, es2, ed2, h2pre, N);
    gat_agg_h1<<<(N + 3) / 4, 256, 0, stream>>>(h2pre, es2, ed2, rowptr, csrsrc, b2,
                                                h2bf, N);

    // --- pool + heads ---
    pool_partial<<<PBLK, 256, 0, stream>>>(h2bf, batch, xsum, cnt, N);
    head_kernel<<<64, 64, 0, stream>>>(xsum, cnt, Wp, bp, Wv, bv, (float*)d_out);
}